// Round 11
// baseline (32.682 us; speedup 1.0000x reference)
//
#include <hip/hip_runtime.h>
#include <math.h>

#define B_ 64
#define S_ 24
#define E_ 128
#define G_ 256
#define N_ (B_ * S_)      // 1536
#define Km_ 100
#define Kch_ 200
#define Ko_ 50
#define Kp_ 50
#define Kc_ 30
#define TOTK_ 435         // 100+200+50+50+1+30+4

#define Vm_ 1000
#define Vch_ 3000
#define Vo_ 500
#define Vp_ 1500
#define Vl_ 700
#define Vc_ 2000
#define TOTROWS_ 8817

// ws float-offsets
#define OFF_MED 0
#define OFF_CHART 1000
#define OFF_OUT 4000
#define OFF_PROC 4500
#define OFF_LAB 6000
#define OFF_COND 6700
#define OFF_GEN 8700
#define OFF_ETH 8702
#define OFF_INS 8712
#define OFF_AGE 8717
#define OFF_PART 8832     // part[435][32] floats (byte 35328, 16B-aligned)
#define OFF_WB   22752    // bf16 weight pool (ushort), byte 91008, 16B-aligned

// bf16 pool ushort-offsets (all 8B-aligned)
#define WB_PROJ 0         // projW  435*128 = 55680
#define WB_W1   55680     // W1     128*256 = 32768
#define WB_W2   88448     // W2     256*256 = 65536
#define WB_FC1  153984    // fc1W   256*128 = 32768
#define WB_TOT  186752

#define NCHUNK_ 32
#define CHUNK_N_ 48       // 1536/32
#define NBLK_B_ 129       // 128 table chunks + 1 small block
#define NTHR_ 512

#define NBLKA_ROWS_ ((TOTROWS_ + 7) / 8)   // 1103 rowmean blocks
#define NBLKA_CVT_ 24                       // bf16 weight-convert blocks

__device__ __forceinline__ int clampi(int v, int hi) {
    return v < 0 ? 0 : (v > hi ? hi : v);
}

// ---- bf16 helpers (RNE convert; bit-shift expand) ----
__device__ __forceinline__ unsigned short f2bf(float f) {
    union { float f; unsigned int u; } v; v.f = f;
    unsigned int u = v.u;
    u += 0x7fffu + ((u >> 16) & 1u);
    return (unsigned short)(u >> 16);
}
__device__ __forceinline__ float bf2f(unsigned short u) {
    union { unsigned int i; float f; } v; v.i = ((unsigned int)u) << 16; return v.f;
}
__device__ __forceinline__ float4 bf2f4(ushort4 w) {
    float4 r;
    r.x = bf2f(w.x); r.y = bf2f(w.y); r.z = bf2f(w.z); r.w = bf2f(w.w);
    return r;
}

// ---------------------------------------------------------------------------
// bf16 convert blocks (kernel A tail): pure streaming copy of the 4 weight
// matrices into the ws bf16 pool. No dependent chains (R8 lesson).
// ---------------------------------------------------------------------------
__device__ void convert_body(
    int cb, int t,
    const float* __restrict__ projW, const float* __restrict__ W1,
    const float* __restrict__ W2,   const float* __restrict__ fc1W,
    unsigned short* __restrict__ wb)
{
    const float* srcs[4] = {projW, W1, W2, fc1W};
    const int n4s[4]  = {55680 / 4, 32768 / 4, 65536 / 4, 32768 / 4};
    const int dsts[4] = {WB_PROJ, WB_W1, WB_W2, WB_FC1};
    #pragma unroll
    for (int a = 0; a < 4; ++a) {
        const float4* s = (const float4*)srcs[a];
        unsigned short* d = wb + dsts[a];
        const int n4 = n4s[a];
        const int chunk = (n4 + NBLKA_CVT_ - 1) / NBLKA_CVT_;
        const int i0 = cb * chunk;
        const int i1 = (i0 + chunk < n4) ? i0 + chunk : n4;
        for (int i = i0 + t; i < i1; i += NTHR_) {
            float4 v = s[i];
            ushort4 o;
            o.x = f2bf(v.x); o.y = f2bf(v.y); o.z = f2bf(v.z); o.w = f2bf(v.w);
            *reinterpret_cast<ushort4*>(d + i * 4) = o;
        }
    }
}

// ---------------------------------------------------------------------------
// Kernel A: one wave per embedding row -> rowmean over E=128, plus 24
// streaming bf16-convert blocks.
// ---------------------------------------------------------------------------
__global__ __launch_bounds__(NTHR_) void rowmeans_kernel(
    const float* __restrict__ medE, const float* __restrict__ chartE,
    const float* __restrict__ outE, const float* __restrict__ procE,
    const float* __restrict__ labE, const float* __restrict__ condE,
    const float* __restrict__ genE, const float* __restrict__ ethE,
    const float* __restrict__ insE, const float* __restrict__ ageE,
    const float* __restrict__ projW, const float* __restrict__ W1,
    const float* __restrict__ W2,   const float* __restrict__ fc1W,
    float* __restrict__ rm, unsigned short* __restrict__ wb)
{
    if (blockIdx.x >= NBLKA_ROWS_) {
        convert_body(blockIdx.x - NBLKA_ROWS_, threadIdx.x, projW, W1, W2, fc1W, wb);
        return;
    }

    int row = blockIdx.x * (NTHR_ / 64) + (threadIdx.x >> 6);
    int lane = threadIdx.x & 63;
    if (row >= TOTROWS_) return;

    const float* src;
    int r = row;
    if (r < Vm_)                  { src = medE; }
    else if ((r -= Vm_)  < Vch_)  { src = chartE; }
    else if ((r -= Vch_) < Vo_)   { src = outE; }
    else if ((r -= Vo_)  < Vp_)   { src = procE; }
    else if ((r -= Vp_)  < Vl_)   { src = labE; }
    else if ((r -= Vl_)  < Vc_)   { src = condE; }
    else if ((r -= Vc_)  < 2)     { src = genE; }
    else if ((r -= 2)    < 10)    { src = ethE; }
    else if ((r -= 10)   < 5)     { src = insE; }
    else                          { r -= 5; src = ageE; }

    float2 v = *reinterpret_cast<const float2*>(src + (size_t)r * E_ + lane * 2);
    float s = v.x + v.y;
    #pragma unroll
    for (int off = 32; off > 0; off >>= 1) s += __shfl_down(s, off, 64);
    if (lane == 0) rm[row] = s * (1.0f / E_);
}

// ---------------------------------------------------------------------------
// Coalesced per-table chunk colsum (R7 verbatim)
// ---------------------------------------------------------------------------
template<int K, int RPI, int CBASE, int RMBASE, int VMAX>
__device__ __forceinline__ void table_chunk(
    const int* __restrict__ idx, const float* __restrict__ rm,
    float* __restrict__ part, int p, int t, float* __restrict__ lds)
{
    constexpr int ACT = K * RPI;
    float acc = 0.0f;
    if (t < ACT) {
        const int kk = t % K;
        const int nr = t / K;
        const int n0 = p * CHUNK_N_;
        #pragma unroll
        for (int i = 0; i < (CHUNK_N_ + RPI - 1) / RPI; ++i) {
            int n = n0 + nr + i * RPI;
            if (nr + i * RPI < CHUNK_N_) {
                int ix = clampi(idx[n * K + kk], VMAX);
                acc += rm[RMBASE + ix];
            }
        }
    }
    lds[t] = acc;
    __syncthreads();
    if (t < K) {
        float s = lds[t];
        #pragma unroll
        for (int r = 1; r < RPI; ++r) s += lds[r * K + t];
        part[(CBASE + t) * NCHUNK_ + p] = s;   // raw sum; scaled in head
    }
}

__global__ __launch_bounds__(NTHR_) void colsum_kernel(
    const int* __restrict__ meds, const int* __restrict__ chart,
    const int* __restrict__ outv, const int* __restrict__ proc,
    const int* __restrict__ lab,  const int* __restrict__ conds,
    const int* __restrict__ demo,
    const float* __restrict__ rm, float* __restrict__ part)
{
    __shared__ float lds_red[NTHR_];
    const int t = threadIdx.x;
    const int bid = blockIdx.x;

    if (bid < 128) {
        const int table = bid >> 5;
        const int p = bid & 31;
        if (table == 0)      table_chunk<Km_, 5, 0,   OFF_MED,  Vm_ -1>(meds,  rm, part, p, t, lds_red);
        else if (table == 1) table_chunk<Kch_,2, 100, OFF_CHART,Vch_-1>(chart, rm, part, p, t, lds_red);
        else if (table == 2) table_chunk<Ko_, 10,300, OFF_OUT,  Vo_ -1>(outv,  rm, part, p, t, lds_red);
        else                 table_chunk<Kp_, 10,350, OFF_PROC, Vp_ -1>(proc,  rm, part, p, t, lds_red);
    } else {
        const int lane = t & 63;
        const int w = t >> 6;
        for (int j = w; j < 35; j += 8) {
            float s = 0.0f;
            if (j == 0) {
                #pragma unroll
                for (int i = 0; i < 24; ++i)
                    s += rm[OFF_LAB + clampi(lab[lane + 64 * i], Vl_ - 1)];
            } else if (j < 31) {
                int kk = j - 1;
                s = rm[OFF_COND + clampi(conds[lane * Kc_ + kk], Vc_ - 1)];
            } else {
                int jj = j - 31;
                int base = (jj == 0) ? OFF_GEN : (jj == 1) ? OFF_ETH :
                           (jj == 2) ? OFF_INS : OFF_AGE;
                s = rm[base + demo[lane * 4 + jj]];
            }
            #pragma unroll
            for (int off = 32; off > 0; off >>= 1) s += __shfl_down(s, off, 64);
            if (lane == 0) part[(400 + j) * NCHUNK_] = s;
        }
    }
}

// ---------------------------------------------------------------------------
// Kernel C: head, bf16 weights (~430 KB total reads). W1 reg-preloaded;
// proj/fc1 float4-equivalent 16-way; W2 8-way. Entropy weight == 1/N exactly.
// ---------------------------------------------------------------------------
__global__ __launch_bounds__(NTHR_) void head_kernel(
    const float* __restrict__ part,
    const unsigned short* __restrict__ wb,
    const float* __restrict__ projb, const float* __restrict__ b1,
    const float* __restrict__ b2,    const float* __restrict__ fc1b,
    const float* __restrict__ fc2W,  const float* __restrict__ fc2b,
    float* __restrict__ outp)
{
    __shared__ float sm[TOTK_];
    __shared__ float xbar[E_];
    __shared__ float h1s[G_];
    __shared__ float h2s[G_];
    __shared__ float fsh[G_ / 2];
    __shared__ float4 red4[16][32];
    __shared__ float4 part4[8][64];
    __shared__ float hred[8];
    __shared__ float oval;

    const int t = threadIdx.x;
    const int lane = t & 63;
    const int oc = t >> 6;      // wave 0..7

    const ushort4* projWp = (const ushort4*)(wb + WB_PROJ);  // [435][32]
    const ushort4* W1p    = (const ushort4*)(wb + WB_W1);    // [128][64]
    const ushort4* W2p    = (const ushort4*)(wb + WB_W2);    // [256][64]
    const ushort4* fc1Wp  = (const ushort4*)(wb + WB_FC1);   // [256][32]

    // ---- W1 register preload (completes during proj stage)
    float4 w1r[16];
    {
        const int k0 = oc * 16;
        #pragma unroll
        for (int i = 0; i < 16; ++i)
            w1r[i] = bf2f4(W1p[(k0 + i) * 64 + lane]);
    }

    // ---- sm[k] = scale * sum_p part[k][p]
    if (t < TOTK_) {
        const float4* pp = (const float4*)(part + t * NCHUNK_);
        float s;
        if (t < 400) {
            s = 0.f;
            #pragma unroll
            for (int j = 0; j < NCHUNK_ / 4; ++j) {
                float4 v = pp[j];
                s += (v.x + v.y) + (v.z + v.w);
            }
            s *= (1.0f / N_);
        } else if (t == 400) {
            s = part[t * NCHUNK_] * (1.0f / N_);
        } else {
            s = part[t * NCHUNK_] * (1.0f / B_);
        }
        sm[t] = s;
    }
    __syncthreads();

    // ---- xbar[128] = sm[435] @ projW + projb : bf16, 16-way k-split
    {
        const int c4 = t & 31;
        const int kg = t >> 5;                     // 0..15
        const int k0 = kg * 28;
        float4 acc = {0.f, 0.f, 0.f, 0.f};
        #pragma unroll
        for (int i = 0; i < 28; ++i) {
            int k = k0 + i;
            if (k < TOTK_) {
                float s = sm[k];
                float4 w = bf2f4(projWp[k * 32 + c4]);
                acc.x += s * w.x; acc.y += s * w.y; acc.z += s * w.z; acc.w += s * w.w;
            }
        }
        red4[kg][c4] = acc;
        __syncthreads();
        if (t < 32) {
            float4 a = red4[0][t];
            #pragma unroll
            for (int j = 1; j < 16; ++j) {
                float4 p = red4[j][t];
                a.x += p.x; a.y += p.y; a.z += p.z; a.w += p.w;
            }
            float4 bb = ((const float4*)projb)[t];
            xbar[4 * t]     = a.x + bb.x;
            xbar[4 * t + 1] = a.y + bb.y;
            xbar[4 * t + 2] = a.z + bb.z;
            xbar[4 * t + 3] = a.w + bb.w;
        }
        __syncthreads();
    }

    // ---- h1[256] = relu(xbar @ W1 + b1) * (1/N) : registers, 8-way
    {
        const int k0 = oc * 16;
        float4 acc = {0.f, 0.f, 0.f, 0.f};
        #pragma unroll
        for (int i = 0; i < 16; ++i) {
            float s = xbar[k0 + i];
            float4 w = w1r[i];
            acc.x += s * w.x; acc.y += s * w.y; acc.z += s * w.z; acc.w += s * w.w;
        }
        part4[oc][lane] = acc;
        __syncthreads();
        if (t < 64) {
            float4 a = part4[0][t];
            #pragma unroll
            for (int j = 1; j < 8; ++j) {
                float4 p = part4[j][t];
                a.x += p.x; a.y += p.y; a.z += p.z; a.w += p.w;
            }
            float4 bb = ((const float4*)b1)[t];
            h1s[4 * t]     = fmaxf(a.x + bb.x, 0.f) * (1.0f / N_);
            h1s[4 * t + 1] = fmaxf(a.y + bb.y, 0.f) * (1.0f / N_);
            h1s[4 * t + 2] = fmaxf(a.z + bb.z, 0.f) * (1.0f / N_);
            h1s[4 * t + 3] = fmaxf(a.w + bb.w, 0.f) * (1.0f / N_);
        }
        __syncthreads();
    }

    // ---- h2[256] = h1 @ W2 + b2 : bf16, 8-way
    {
        const int k0 = oc * 32, k1 = k0 + 32;
        float4 acc = {0.f, 0.f, 0.f, 0.f};
        #pragma unroll 8
        for (int k = k0; k < k1; ++k) {
            float s = h1s[k];
            float4 w = bf2f4(W2p[k * 64 + lane]);
            acc.x += s * w.x; acc.y += s * w.y; acc.z += s * w.z; acc.w += s * w.w;
        }
        part4[oc][lane] = acc;
        __syncthreads();
        if (t < 64) {
            float4 a = part4[0][t];
            #pragma unroll
            for (int j = 1; j < 8; ++j) {
                float4 p = part4[j][t];
                a.x += p.x; a.y += p.y; a.z += p.z; a.w += p.w;
            }
            float4 bb = ((const float4*)b2)[t];
            h2s[4 * t]     = a.x + bb.x;
            h2s[4 * t + 1] = a.y + bb.y;
            h2s[4 * t + 2] = a.z + bb.z;
            h2s[4 * t + 3] = a.w + bb.w;
        }
        __syncthreads();
    }

    // ---- f[128] = relu(h2 @ fc1W + fc1b) : bf16, 16-way
    {
        const int c4 = t & 31;
        const int kg = t >> 5;                     // 0..15
        const int k0 = kg * 16;
        float4 acc = {0.f, 0.f, 0.f, 0.f};
        #pragma unroll 8
        for (int i = 0; i < 16; ++i) {
            int k = k0 + i;
            float s = h2s[k];
            float4 w = bf2f4(fc1Wp[k * 32 + c4]);
            acc.x += s * w.x; acc.y += s * w.y; acc.z += s * w.z; acc.w += s * w.w;
        }
        red4[kg][c4] = acc;
        __syncthreads();
        if (t < 32) {
            float4 a = red4[0][t];
            #pragma unroll
            for (int j = 1; j < 16; ++j) {
                float4 p = red4[j][t];
                a.x += p.x; a.y += p.y; a.z += p.z; a.w += p.w;
            }
            float4 bb = ((const float4*)fc1b)[t];
            fsh[4 * t]     = fmaxf(a.x + bb.x, 0.f);
            fsh[4 * t + 1] = fmaxf(a.y + bb.y, 0.f);
            fsh[4 * t + 2] = fmaxf(a.z + bb.z, 0.f);
            fsh[4 * t + 3] = fmaxf(a.w + bb.w, 0.f);
        }
        __syncthreads();
    }

    // ---- o = f . fc2_W + fc2_b ; write outputs
    {
        float p = (t < G_ / 2) ? fsh[t] * fc2W[t] : 0.f;
        #pragma unroll
        for (int off = 32; off > 0; off >>= 1) p += __shfl_down(p, off, 64);
        if (lane == 0) hred[oc] = p;
        __syncthreads();
        if (t == 0) {
            float o = fc2b[0];
            #pragma unroll
            for (int j = 0; j < 8; ++j) o += hred[j];
            oval = o;
        }
        __syncthreads();
        const float o = oval;
        const float sig = 1.0f / (1.0f + expf(-o));
        if (t < B_)            outp[t] = sig;   // output 0: sigmoid(o)
        else if (t < 2 * B_)   outp[t] = o;     // output 1: o
    }
}

// ---------------------------------------------------------------------------
extern "C" void kernel_launch(void* const* d_in, const int* in_sizes, int n_in,
                              void* d_out, int out_size, void* d_ws, size_t ws_size,
                              hipStream_t stream) {
    const int* meds  = (const int*)d_in[0];
    const int* chart = (const int*)d_in[1];
    const int* outv  = (const int*)d_in[2];
    const int* proc  = (const int*)d_in[3];
    const int* lab   = (const int*)d_in[4];
    const int* conds = (const int*)d_in[5];
    const int* demo  = (const int*)d_in[6];
    const float* medE   = (const float*)d_in[7];
    const float* chartE = (const float*)d_in[8];
    const float* outE   = (const float*)d_in[9];
    const float* procE  = (const float*)d_in[10];
    const float* labE   = (const float*)d_in[11];
    const float* condE  = (const float*)d_in[12];
    const float* genE   = (const float*)d_in[13];
    const float* ethE   = (const float*)d_in[14];
    const float* insE   = (const float*)d_in[15];
    const float* ageE   = (const float*)d_in[16];
    const float* projW  = (const float*)d_in[17];
    const float* projb  = (const float*)d_in[18];
    const float* W1     = (const float*)d_in[19];
    const float* b1     = (const float*)d_in[20];
    const float* W2     = (const float*)d_in[21];
    const float* b2     = (const float*)d_in[22];
    const float* fc1W   = (const float*)d_in[23];
    const float* fc1b   = (const float*)d_in[24];
    const float* fc2W   = (const float*)d_in[25];
    const float* fc2b   = (const float*)d_in[26];

    float* rm   = (float*)d_ws;                          // rm[8817]
    float* part = (float*)d_ws + OFF_PART;               // part[435][32]
    unsigned short* wb = (unsigned short*)((float*)d_ws + OFF_WB);  // bf16 pool
    float* outp = (float*)d_out;                         // 128 floats

    // A: row means + streaming bf16 weight conversion
    rowmeans_kernel<<<NBLKA_ROWS_ + NBLKA_CVT_, NTHR_, 0, stream>>>(
        medE, chartE, outE, procE, labE, condE, genE, ethE, insE, ageE,
        projW, W1, W2, fc1W, rm, wb);

    // B: coalesced colsum partials
    colsum_kernel<<<NBLK_B_, NTHR_, 0, stream>>>(
        meds, chart, outv, proc, lab, conds, demo, rm, part);

    // C: head on bf16 weights (~430 KB)
    head_kernel<<<1, NTHR_, 0, stream>>>(
        part, wb, projb, b1, b2, fc1b, fc2W, fc2b, outp);
}

// Round 12
// 25.091 us; speedup vs baseline: 1.3025x; 1.3025x over previous
//
#include <hip/hip_runtime.h>
#include <math.h>

#define B_ 64
#define S_ 24
#define E_ 128
#define G_ 256
#define N_ (B_ * S_)      // 1536
#define Km_ 100
#define Kch_ 200
#define Ko_ 50
#define Kp_ 50
#define Kc_ 30
#define TOTK_ 435         // 100+200+50+50+1+30+4

#define Vm_ 1000
#define Vch_ 3000
#define Vo_ 500
#define Vp_ 1500
#define Vl_ 700
#define Vc_ 2000
#define TOTROWS_ 8817

// ws float-offsets
#define OFF_MED 0
#define OFF_CHART 1000
#define OFF_OUT 4000
#define OFF_PROC 4500
#define OFF_LAB 6000
#define OFF_COND 6700
#define OFF_GEN 8700
#define OFF_ETH 8702
#define OFF_INS 8712
#define OFF_AGE 8717
#define OFF_PART 8832     // part[435][32] floats (byte 35328, 16B-aligned)

#define NCHUNK_ 32
#define CHUNK_N_ 48       // 1536/32
#define NBLK_B_ 129       // 128 table chunks + 1 small block
#define NTHR_ 512

__device__ __forceinline__ int clampi(int v, int hi) {
    return v < 0 ? 0 : (v > hi ? hi : v);
}

// ---------------------------------------------------------------------------
// Kernel A: one wave per embedding row -> rowmean over E=128
// ---------------------------------------------------------------------------
__global__ __launch_bounds__(NTHR_) void rowmeans_kernel(
    const float* __restrict__ medE, const float* __restrict__ chartE,
    const float* __restrict__ outE, const float* __restrict__ procE,
    const float* __restrict__ labE, const float* __restrict__ condE,
    const float* __restrict__ genE, const float* __restrict__ ethE,
    const float* __restrict__ insE, const float* __restrict__ ageE,
    float* __restrict__ rm)
{
    int row = blockIdx.x * (NTHR_ / 64) + (threadIdx.x >> 6);
    int lane = threadIdx.x & 63;
    if (row >= TOTROWS_) return;

    const float* src;
    int r = row;
    if (r < Vm_)                  { src = medE; }
    else if ((r -= Vm_)  < Vch_)  { src = chartE; }
    else if ((r -= Vch_) < Vo_)   { src = outE; }
    else if ((r -= Vo_)  < Vp_)   { src = procE; }
    else if ((r -= Vp_)  < Vl_)   { src = labE; }
    else if ((r -= Vl_)  < Vc_)   { src = condE; }
    else if ((r -= Vc_)  < 2)     { src = genE; }
    else if ((r -= 2)    < 10)    { src = ethE; }
    else if ((r -= 10)   < 5)     { src = insE; }
    else                          { r -= 5; src = ageE; }

    float2 v = *reinterpret_cast<const float2*>(src + (size_t)r * E_ + lane * 2);
    float s = v.x + v.y;
    #pragma unroll
    for (int off = 32; off > 0; off >>= 1) s += __shfl_down(s, off, 64);
    if (lane == 0) rm[row] = s * (1.0f / E_);
}

// ---------------------------------------------------------------------------
// Coalesced per-table chunk colsum
// ---------------------------------------------------------------------------
template<int K, int RPI, int CBASE, int RMBASE, int VMAX>
__device__ __forceinline__ void table_chunk(
    const int* __restrict__ idx, const float* __restrict__ rm,
    float* __restrict__ part, int p, int t, float* __restrict__ lds)
{
    constexpr int ACT = K * RPI;
    float acc = 0.0f;
    if (t < ACT) {
        const int kk = t % K;
        const int nr = t / K;
        const int n0 = p * CHUNK_N_;
        #pragma unroll
        for (int i = 0; i < (CHUNK_N_ + RPI - 1) / RPI; ++i) {
            int n = n0 + nr + i * RPI;
            if (nr + i * RPI < CHUNK_N_) {
                int ix = clampi(idx[n * K + kk], VMAX);
                acc += rm[RMBASE + ix];
            }
        }
    }
    lds[t] = acc;
    __syncthreads();
    if (t < K) {
        float s = lds[t];
        #pragma unroll
        for (int r = 1; r < RPI; ++r) s += lds[r * K + t];
        part[(CBASE + t) * NCHUNK_ + p] = s;   // raw sum; scaled in head
    }
}

__global__ __launch_bounds__(NTHR_) void colsum_kernel(
    const int* __restrict__ meds, const int* __restrict__ chart,
    const int* __restrict__ outv, const int* __restrict__ proc,
    const int* __restrict__ lab,  const int* __restrict__ conds,
    const int* __restrict__ demo,
    const float* __restrict__ rm, float* __restrict__ part)
{
    __shared__ float lds_red[NTHR_];
    const int t = threadIdx.x;
    const int bid = blockIdx.x;

    if (bid < 128) {
        const int table = bid >> 5;
        const int p = bid & 31;
        if (table == 0)      table_chunk<Km_, 5, 0,   OFF_MED,  Vm_ -1>(meds,  rm, part, p, t, lds_red);
        else if (table == 1) table_chunk<Kch_,2, 100, OFF_CHART,Vch_-1>(chart, rm, part, p, t, lds_red);
        else if (table == 2) table_chunk<Ko_, 10,300, OFF_OUT,  Vo_ -1>(outv,  rm, part, p, t, lds_red);
        else                 table_chunk<Kp_, 10,350, OFF_PROC, Vp_ -1>(proc,  rm, part, p, t, lds_red);
    } else {
        const int lane = t & 63;
        const int w = t >> 6;
        for (int j = w; j < 35; j += 8) {
            float s = 0.0f;
            if (j == 0) {
                #pragma unroll
                for (int i = 0; i < 24; ++i)
                    s += rm[OFF_LAB + clampi(lab[lane + 64 * i], Vl_ - 1)];
            } else if (j < 31) {
                int kk = j - 1;
                s = rm[OFF_COND + clampi(conds[lane * Kc_ + kk], Vc_ - 1)];
            } else {
                int jj = j - 31;
                int base = (jj == 0) ? OFF_GEN : (jj == 1) ? OFF_ETH :
                           (jj == 2) ? OFF_INS : OFF_AGE;
                s = rm[base + demo[lane * 4 + jj]];
            }
            #pragma unroll
            for (int off = 32; off > 0; off >>= 1) s += __shfl_down(s, off, 64);
            if (lane == 0) part[(400 + j) * NCHUNK_] = s;
        }
    }
}

// ---------------------------------------------------------------------------
// Kernel C: head (5 stages) with W1 register preload (latency hidden under
// the proj stage) and float4/16-way proj + fc1 stages.
// Entropy weight over identical rows == exactly 1/N.
// ---------------------------------------------------------------------------
__global__ __launch_bounds__(NTHR_) void head_kernel(
    const float* __restrict__ part,
    const float* __restrict__ projW, const float* __restrict__ projb,
    const float* __restrict__ W1, const float* __restrict__ b1,
    const float* __restrict__ W2, const float* __restrict__ b2,
    const float* __restrict__ fc1W, const float* __restrict__ fc1b,
    const float* __restrict__ fc2W, const float* __restrict__ fc2b,
    float* __restrict__ outp)
{
    __shared__ float sm[TOTK_];
    __shared__ float xbar[E_];
    __shared__ float h1s[G_];
    __shared__ float h2s[G_];
    __shared__ float fsh[G_ / 2];
    __shared__ float4 red4[16][32];
    __shared__ float4 part4[8][64];
    __shared__ float hred[8];
    __shared__ float oval;

    const int t = threadIdx.x;
    const int lane = t & 63;
    const int oc = t >> 6;      // wave 0..7

    // ---- W1 register preload: rows oc*16..oc*16+15, float4 column `lane`.
    const float4* W1p = (const float4*)W1;     // [128][64]
    float4 w1r[16];
    {
        const int k0 = oc * 16;
        #pragma unroll
        for (int i = 0; i < 16; ++i)
            w1r[i] = W1p[(k0 + i) * 64 + lane];
    }

    // ---- sm[k] = scale * sum_p part[k][p]
    if (t < TOTK_) {
        const float4* pp = (const float4*)(part + t * NCHUNK_);
        float s;
        if (t < 400) {
            s = 0.f;
            #pragma unroll
            for (int j = 0; j < NCHUNK_ / 4; ++j) {
                float4 v = pp[j];
                s += (v.x + v.y) + (v.z + v.w);
            }
            s *= (1.0f / N_);
        } else if (t == 400) {
            s = part[t * NCHUNK_] * (1.0f / N_);
        } else {
            s = part[t * NCHUNK_] * (1.0f / B_);
        }
        sm[t] = s;
    }
    __syncthreads();

    // ---- xbar[128] = sm[435] @ projW[435,128] + projb : float4, 16-way
    {
        const float4* Wp = (const float4*)projW;   // [435][32]
        const int c4 = t & 31;
        const int kg = t >> 5;                     // 0..15
        const int k0 = kg * 28;
        float4 acc = {0.f, 0.f, 0.f, 0.f};
        #pragma unroll
        for (int i = 0; i < 28; ++i) {
            int k = k0 + i;
            if (k < TOTK_) {
                float s = sm[k];
                float4 w = Wp[k * 32 + c4];
                acc.x += s * w.x; acc.y += s * w.y; acc.z += s * w.z; acc.w += s * w.w;
            }
        }
        red4[kg][c4] = acc;
        __syncthreads();
        if (t < 32) {
            float4 a = red4[0][t];
            #pragma unroll
            for (int j = 1; j < 16; ++j) {
                float4 p = red4[j][t];
                a.x += p.x; a.y += p.y; a.z += p.z; a.w += p.w;
            }
            float4 bb = ((const float4*)projb)[t];
            xbar[4 * t]     = a.x + bb.x;
            xbar[4 * t + 1] = a.y + bb.y;
            xbar[4 * t + 2] = a.z + bb.z;
            xbar[4 * t + 3] = a.w + bb.w;
        }
        __syncthreads();
    }

    // ---- h1[256] = relu(xbar @ W1 + b1) * (1/N) : registers, 8-way
    {
        const int k0 = oc * 16;
        float4 acc = {0.f, 0.f, 0.f, 0.f};
        #pragma unroll
        for (int i = 0; i < 16; ++i) {
            float s = xbar[k0 + i];
            float4 w = w1r[i];
            acc.x += s * w.x; acc.y += s * w.y; acc.z += s * w.z; acc.w += s * w.w;
        }
        part4[oc][lane] = acc;
        __syncthreads();
        if (t < 64) {
            float4 a = part4[0][t];
            #pragma unroll
            for (int j = 1; j < 8; ++j) {
                float4 p = part4[j][t];
                a.x += p.x; a.y += p.y; a.z += p.z; a.w += p.w;
            }
            float4 bb = ((const float4*)b1)[t];
            h1s[4 * t]     = fmaxf(a.x + bb.x, 0.f) * (1.0f / N_);
            h1s[4 * t + 1] = fmaxf(a.y + bb.y, 0.f) * (1.0f / N_);
            h1s[4 * t + 2] = fmaxf(a.z + bb.z, 0.f) * (1.0f / N_);
            h1s[4 * t + 3] = fmaxf(a.w + bb.w, 0.f) * (1.0f / N_);
        }
        __syncthreads();
    }

    // ---- h2[256] = h1 @ W2[256,256] + b2 : float4, 8-way
    {
        const float4* Wp = (const float4*)W2;      // [256][64]
        const int k0 = oc * 32, k1 = k0 + 32;
        float4 acc = {0.f, 0.f, 0.f, 0.f};
        #pragma unroll 8
        for (int k = k0; k < k1; ++k) {
            float s = h1s[k];
            float4 w = Wp[k * 64 + lane];
            acc.x += s * w.x; acc.y += s * w.y; acc.z += s * w.z; acc.w += s * w.w;
        }
        part4[oc][lane] = acc;
        __syncthreads();
        if (t < 64) {
            float4 a = part4[0][t];
            #pragma unroll
            for (int j = 1; j < 8; ++j) {
                float4 p = part4[j][t];
                a.x += p.x; a.y += p.y; a.z += p.z; a.w += p.w;
            }
            float4 bb = ((const float4*)b2)[t];
            h2s[4 * t]     = a.x + bb.x;
            h2s[4 * t + 1] = a.y + bb.y;
            h2s[4 * t + 2] = a.z + bb.z;
            h2s[4 * t + 3] = a.w + bb.w;
        }
        __syncthreads();
    }

    // ---- f[128] = relu(h2 @ fc1W[256,128] + fc1b) : float4, 16-way
    {
        const float4* Wp = (const float4*)fc1W;    // [256][32]
        const int c4 = t & 31;
        const int kg = t >> 5;                     // 0..15
        const int k0 = kg * 16;
        float4 acc = {0.f, 0.f, 0.f, 0.f};
        #pragma unroll 8
        for (int i = 0; i < 16; ++i) {
            int k = k0 + i;
            float s = h2s[k];
            float4 w = Wp[k * 32 + c4];
            acc.x += s * w.x; acc.y += s * w.y; acc.z += s * w.z; acc.w += s * w.w;
        }
        red4[kg][c4] = acc;
        __syncthreads();
        if (t < 32) {
            float4 a = red4[0][t];
            #pragma unroll
            for (int j = 1; j < 16; ++j) {
                float4 p = red4[j][t];
                a.x += p.x; a.y += p.y; a.z += p.z; a.w += p.w;
            }
            float4 bb = ((const float4*)fc1b)[t];
            fsh[4 * t]     = fmaxf(a.x + bb.x, 0.f);
            fsh[4 * t + 1] = fmaxf(a.y + bb.y, 0.f);
            fsh[4 * t + 2] = fmaxf(a.z + bb.z, 0.f);
            fsh[4 * t + 3] = fmaxf(a.w + bb.w, 0.f);
        }
        __syncthreads();
    }

    // ---- o = f . fc2_W + fc2_b ; write outputs
    {
        float p = (t < G_ / 2) ? fsh[t] * fc2W[t] : 0.f;
        #pragma unroll
        for (int off = 32; off > 0; off >>= 1) p += __shfl_down(p, off, 64);
        if (lane == 0) hred[oc] = p;
        __syncthreads();
        if (t == 0) {
            float o = fc2b[0];
            #pragma unroll
            for (int j = 0; j < 8; ++j) o += hred[j];
            oval = o;
        }
        __syncthreads();
        const float o = oval;
        const float sig = 1.0f / (1.0f + expf(-o));
        if (t < B_)            outp[t] = sig;   // output 0: sigmoid(o)
        else if (t < 2 * B_)   outp[t] = o;     // output 1: o
    }
}

// ---------------------------------------------------------------------------
extern "C" void kernel_launch(void* const* d_in, const int* in_sizes, int n_in,
                              void* d_out, int out_size, void* d_ws, size_t ws_size,
                              hipStream_t stream) {
    const int* meds  = (const int*)d_in[0];
    const int* chart = (const int*)d_in[1];
    const int* outv  = (const int*)d_in[2];
    const int* proc  = (const int*)d_in[3];
    const int* lab   = (const int*)d_in[4];
    const int* conds = (const int*)d_in[5];
    const int* demo  = (const int*)d_in[6];
    const float* medE   = (const float*)d_in[7];
    const float* chartE = (const float*)d_in[8];
    const float* outE   = (const float*)d_in[9];
    const float* procE  = (const float*)d_in[10];
    const float* labE   = (const float*)d_in[11];
    const float* condE  = (const float*)d_in[12];
    const float* genE   = (const float*)d_in[13];
    const float* ethE   = (const float*)d_in[14];
    const float* insE   = (const float*)d_in[15];
    const float* ageE   = (const float*)d_in[16];
    const float* projW  = (const float*)d_in[17];
    const float* projb  = (const float*)d_in[18];
    const float* W1     = (const float*)d_in[19];
    const float* b1     = (const float*)d_in[20];
    const float* W2     = (const float*)d_in[21];
    const float* b2     = (const float*)d_in[22];
    const float* fc1W   = (const float*)d_in[23];
    const float* fc1b   = (const float*)d_in[24];
    const float* fc2W   = (const float*)d_in[25];
    const float* fc2b   = (const float*)d_in[26];

    float* rm   = (float*)d_ws;                 // rm[8817]
    float* part = (float*)d_ws + OFF_PART;      // part[435][32]
    float* outp = (float*)d_out;                // 128 floats

    // A: row means
    int blocksA = (TOTROWS_ + (NTHR_ / 64) - 1) / (NTHR_ / 64);
    rowmeans_kernel<<<blocksA, NTHR_, 0, stream>>>(
        medE, chartE, outE, procE, labE, condE, genE, ethE, insE, ageE, rm);

    // B: coalesced colsum partials
    colsum_kernel<<<NBLK_B_, NTHR_, 0, stream>>>(
        meds, chart, outv, proc, lab, conds, demo, rm, part);

    // C: head (W1 reg-preload, float4 16-way proj/fc1)
    head_kernel<<<1, NTHR_, 0, stream>>>(
        part, projW, projb, W1, b1, W2, b2, fc1W, fc1b, fc2W, fc2b, outp);
}